// Round 5
// baseline (332.193 us; speedup 1.0000x reference)
//
#include <hip/hip_runtime.h>
#include <hip/hip_bf16.h>
#include <cstdint>

#define H_  8
#define B_  4
#define NQ  2048
#define NKV 2048
#define DF  160   // 8*16 + 32 flattened features per head

typedef __attribute__((ext_vector_type(8))) short bf16x8;
typedef __attribute__((ext_vector_type(4))) float f32x4;

__constant__ int   c_grade[16]  = {0,1,1,1,1,2,2,2,2,2,2,3,3,3,3,4};
__constant__ float c_metric[16] = {1.f,1.f,-1.f,-1.f,-1.f,-1.f,-1.f,-1.f,
                                   1.f,1.f,1.f,1.f,1.f,1.f,-1.f,-1.f};

// (1/sqrt(160)) * log2(e)  -- folded into Wq so softmax uses exp2 directly
#define SCALE_LOG2E 0.11405506f

__device__ __forceinline__ unsigned short f2bf(float f) {
    union { float f; unsigned u; } v; v.f = f;
    return (unsigned short)((v.u + 0x7FFFu + ((v.u >> 16) & 1u)) >> 16);
}

// =============== Weight expansion: grade-basis -> dense bf16 [j][k] =============
// Wq: j = h*160 + pos (pos = c*16+x | 128+cs), k = [256 mv][64 s][1 bias][pad->352]
__global__ __launch_bounds__(256) void expand_wq(
    const float* __restrict__ wmv, const float* __restrict__ ws2mv,
    const float* __restrict__ wmv2s, const float* __restrict__ ws,
    const float* __restrict__ bmv, const float* __restrict__ bs,
    unsigned short* __restrict__ Wq)
{
    const int j = blockIdx.x;           // 0..1279
    const int h = j / 160, pos = j % 160;
    for (int k = threadIdx.x; k < 352; k += 256) {
        float val = 0.f;
        if (pos < 128) {
            int c = pos >> 4, x = pos & 15, o = c * 8 + h, g = c_grade[x];
            if (k < 256)       { if ((k & 15) == x) val = wmv[(o*16 + (k>>4))*5 + g]; }
            else if (k < 320)  { if (x == 0) val = ws2mv[o*64 + (k-256)]; }
            else if (k == 320) { if (x == 0) val = bmv[o]; }
        } else {
            int cs = pos - 128, o2 = cs * 8 + h;
            if (k < 256)       { if ((k & 15) == 0) val = wmv2s[o2*16 + (k>>4)]; }
            else if (k < 320)  val = ws[o2*64 + (k-256)];
            else if (k == 320) val = bs[o2];
        }
        Wq[(size_t)j*352 + k] = f2bf(val * SCALE_LOG2E);
    }
}

// Wkv: j<160 = K features (METRIC folded), j in [160,320) = V features
__global__ __launch_bounds__(256) void expand_wkv(
    const float* __restrict__ wmv, const float* __restrict__ ws2mv,
    const float* __restrict__ wmv2s, const float* __restrict__ ws,
    const float* __restrict__ bmv, const float* __restrict__ bs,
    unsigned short* __restrict__ Wkv)
{
    const int j = blockIdx.x;           // 0..319
    const int side = j / 160, pos = j % 160;
    for (int k = threadIdx.x; k < 352; k += 256) {
        float val = 0.f, mult = 1.f;
        if (pos < 128) {
            int c = pos >> 4, x = pos & 15, o = side * 8 + c, g = c_grade[x];
            if (side == 0) mult = c_metric[x];
            if (k < 256)       { if ((k & 15) == x) val = wmv[(o*16 + (k>>4))*5 + g]; }
            else if (k < 320)  { if (x == 0) val = ws2mv[o*64 + (k-256)]; }
            else if (k == 320) { if (x == 0) val = bmv[o]; }
        } else {
            int s = pos - 128, o2 = side * 32 + s;
            if (k < 256)       { if ((k & 15) == 0) val = wmv2s[o2*16 + (k>>4)]; }
            else if (k < 320)  val = ws[o2*64 + (k-256)];
            else if (k == 320) val = bs[o2];
        }
        Wkv[(size_t)j*352 + k] = f2bf(val * mult);
    }
}

// Wo: j<256 = out mv (o2*16+x), j in [256,320) = out s; k = h*160+pos features + bias@1280
__global__ __launch_bounds__(256) void expand_wo(
    const float* __restrict__ wmv, const float* __restrict__ ws2mv,
    const float* __restrict__ wmv2s, const float* __restrict__ ws,
    const float* __restrict__ bmv, const float* __restrict__ bs,
    unsigned short* __restrict__ Wo)
{
    const int j = blockIdx.x;           // 0..319
    for (int k = threadIdx.x; k < 1408; k += 256) {
        float val = 0.f;
        if (j < 256) {
            int o2 = j >> 4, x = j & 15, g = c_grade[x];
            if (k < 1280) {
                int hh = k / 160, pp = k % 160;
                if (pp < 128) { if ((pp & 15) == x) val = wmv[(o2*64 + hh*8 + (pp>>4))*5 + g]; }
                else          { if (x == 0) val = ws2mv[o2*256 + hh*32 + (pp-128)]; }
            } else if (k == 1280) { if (x == 0) val = bmv[o2]; }
        } else {
            int o2 = j - 256;
            if (k < 1280) {
                int hh = k / 160, pp = k % 160;
                if (pp < 128) { if ((pp & 15) == 0) val = wmv2s[o2*64 + hh*8 + (pp>>4)]; }
                else          val = ws[o2*256 + hh*32 + (pp-128)];
            } else if (k == 1280) val = bs[o2];
        }
        Wo[(size_t)j*1408 + k] = f2bf(val);
    }
}

// =============== GEMM projections: 64 tokens x 160-col slice per block ==========
#define ASTR 360   // A_sh stride (shorts): 16B-aligned rows, 2-way-free banks
#define WSTR 40    // Wsh stride

// Q projection: C[tok][h*160+pos] -> Qbuf[b][h][n][pos]
__global__ __launch_bounds__(256) void gemm_q(
    const float* __restrict__ mvq, const float* __restrict__ sq,
    const unsigned short* __restrict__ Wq, unsigned short* __restrict__ Qbuf)
{
    const int tok0 = blockIdx.x * 64, h = blockIdx.y;
    const int b = tok0 / NQ, n0 = tok0 % NQ;
    const int t = threadIdx.x, w = t >> 6, lane = t & 63, l16 = lane & 15, lq = lane >> 4;

    __shared__ __align__(16) unsigned short Ash[64][ASTR];
    __shared__ __align__(16) unsigned short Wsh[160][WSTR];

    const float4* mv4 = (const float4*)(mvq + (size_t)tok0 * 256);
    const float4* s4  = (const float4*)(sq  + (size_t)tok0 * 64);
    #pragma unroll
    for (int r = 0; r < 20; ++r) {
        int slot = t + 256 * r;           // 5120 = 64 tok x 80 float4
        int tok = slot / 80, q = slot % 80;
        float4 v = (q < 64) ? mv4[tok * 64 + q] : s4[tok * 16 + (q - 64)];
        int col = (q < 64) ? q * 4 : 256 + (q - 64) * 4;
        unsigned lo = (unsigned)f2bf(v.x) | ((unsigned)f2bf(v.y) << 16);
        unsigned hi = (unsigned)f2bf(v.z) | ((unsigned)f2bf(v.w) << 16);
        uint2 u; u.x = lo; u.y = hi;
        *(uint2*)&Ash[tok][col] = u;
    }
    #pragma unroll
    for (int r = 0; r < 9; ++r) {
        int idx = t + 256 * r;            // 2304 = 64 tok x 36 pad cols
        int tok = idx / 36, cc = idx % 36;
        Ash[tok][320 + cc] = (cc == 0) ? (unsigned short)0x3F80 : (unsigned short)0;
    }
    __syncthreads();

    bf16x8 af[11];
    #pragma unroll
    for (int ks = 0; ks < 11; ++ks)
        af[ks] = *(const bf16x8*)&Ash[w * 16 + l16][ks * 32 + lq * 8];

    f32x4 acc[10];
    #pragma unroll
    for (int nt = 0; nt < 10; ++nt) acc[nt] = f32x4{0.f, 0.f, 0.f, 0.f};

    const unsigned short* Wbase = Wq + (size_t)h * 160 * 352;
    for (int ks = 0; ks < 11; ++ks) {
        __syncthreads();
        #pragma unroll
        for (int r = 0; r < 3; ++r) {
            int s = t + 256 * r;          // 640 uint4 = 160 rows x 4
            if (s < 640) {
                int row = s >> 2, c4 = s & 3;
                *(uint4*)&Wsh[row][c4 * 8] =
                    *(const uint4*)(Wbase + (size_t)row * 352 + ks * 32 + c4 * 8);
            }
        }
        __syncthreads();
        #pragma unroll
        for (int nt = 0; nt < 10; ++nt) {
            bf16x8 wf = *(const bf16x8*)&Wsh[nt * 16 + l16][lq * 8];
            acc[nt] = __builtin_amdgcn_mfma_f32_16x16x32_bf16(af[ks], wf, acc[nt], 0, 0, 0);
        }
    }

    unsigned short* qb = Qbuf + ((size_t)(b * H_ + h) * NQ + n0) * DF;
    #pragma unroll
    for (int nt = 0; nt < 10; ++nt)
        #pragma unroll
        for (int r = 0; r < 4; ++r) {
            int tok = w * 16 + 4 * lq + r;
            qb[(size_t)tok * DF + nt * 16 + l16] = f2bf(acc[nt][r]);
        }
}

// KV projection: slice 0 -> Kbuf (row-major), slice 1 -> Vt (transposed)
__global__ __launch_bounds__(256) void gemm_kv(
    const float* __restrict__ mvkv, const float* __restrict__ skv,
    const unsigned short* __restrict__ Wkv,
    unsigned short* __restrict__ Kbuf, unsigned short* __restrict__ Vtbuf)
{
    const int tok0 = blockIdx.x * 64, slice = blockIdx.y;
    const int b = tok0 / NKV, n0 = tok0 % NKV;
    const int t = threadIdx.x, w = t >> 6, lane = t & 63, l16 = lane & 15, lq = lane >> 4;

    __shared__ __align__(16) unsigned short Ash[64][ASTR];
    __shared__ __align__(16) unsigned short Wsh[160][WSTR];

    const float4* mv4 = (const float4*)(mvkv + (size_t)tok0 * 256);
    const float4* s4  = (const float4*)(skv  + (size_t)tok0 * 64);
    #pragma unroll
    for (int r = 0; r < 20; ++r) {
        int slot = t + 256 * r;
        int tok = slot / 80, q = slot % 80;
        float4 v = (q < 64) ? mv4[tok * 64 + q] : s4[tok * 16 + (q - 64)];
        int col = (q < 64) ? q * 4 : 256 + (q - 64) * 4;
        unsigned lo = (unsigned)f2bf(v.x) | ((unsigned)f2bf(v.y) << 16);
        unsigned hi = (unsigned)f2bf(v.z) | ((unsigned)f2bf(v.w) << 16);
        uint2 u; u.x = lo; u.y = hi;
        *(uint2*)&Ash[tok][col] = u;
    }
    #pragma unroll
    for (int r = 0; r < 9; ++r) {
        int idx = t + 256 * r;
        int tok = idx / 36, cc = idx % 36;
        Ash[tok][320 + cc] = (cc == 0) ? (unsigned short)0x3F80 : (unsigned short)0;
    }
    __syncthreads();

    bf16x8 af[11];
    #pragma unroll
    for (int ks = 0; ks < 11; ++ks)
        af[ks] = *(const bf16x8*)&Ash[w * 16 + l16][ks * 32 + lq * 8];

    f32x4 acc[10];
    #pragma unroll
    for (int nt = 0; nt < 10; ++nt) acc[nt] = f32x4{0.f, 0.f, 0.f, 0.f};

    const unsigned short* Wbase = Wkv + (size_t)slice * 160 * 352;
    for (int ks = 0; ks < 11; ++ks) {
        __syncthreads();
        #pragma unroll
        for (int r = 0; r < 3; ++r) {
            int s = t + 256 * r;
            if (s < 640) {
                int row = s >> 2, c4 = s & 3;
                *(uint4*)&Wsh[row][c4 * 8] =
                    *(const uint4*)(Wbase + (size_t)row * 352 + ks * 32 + c4 * 8);
            }
        }
        __syncthreads();
        #pragma unroll
        for (int nt = 0; nt < 10; ++nt) {
            bf16x8 wf = *(const bf16x8*)&Wsh[nt * 16 + l16][lq * 8];
            acc[nt] = __builtin_amdgcn_mfma_f32_16x16x32_bf16(af[ks], wf, acc[nt], 0, 0, 0);
        }
    }

    if (slice == 0) {
        unsigned short* kb = Kbuf + ((size_t)b * NKV + n0) * DF;
        #pragma unroll
        for (int nt = 0; nt < 10; ++nt)
            #pragma unroll
            for (int r = 0; r < 4; ++r) {
                int tok = w * 16 + 4 * lq + r;
                kb[(size_t)tok * DF + nt * 16 + l16] = f2bf(acc[nt][r]);
            }
    } else {
        unsigned short* vb = Vtbuf + (size_t)b * DF * NKV;
        #pragma unroll
        for (int nt = 0; nt < 10; ++nt) {
            int pos = nt * 16 + l16;
            unsigned lo = (unsigned)f2bf(acc[nt][0]) | ((unsigned)f2bf(acc[nt][1]) << 16);
            unsigned hi = (unsigned)f2bf(acc[nt][2]) | ((unsigned)f2bf(acc[nt][3]) << 16);
            uint2 u; u.x = lo; u.y = hi;
            *(uint2*)(vb + (size_t)pos * NKV + n0 + w * 16 + 4 * lq) = u;
        }
    }
}

// Output projection: A = Hbuf (1280 feats + bias, 4 k-chunks), C -> out (f32)
__global__ __launch_bounds__(256) void gemm_o(
    const unsigned short* __restrict__ Hb, const unsigned short* __restrict__ Wo,
    float* __restrict__ out)
{
    const int tok0 = blockIdx.x * 64, slice = blockIdx.y;
    const int b = tok0 / NQ, n0 = tok0 % NQ;
    const int t = threadIdx.x, w = t >> 6, lane = t & 63, l16 = lane & 15, lq = lane >> 4;

    __shared__ __align__(16) unsigned short Ash[64][ASTR];
    __shared__ __align__(16) unsigned short Wsh[160][WSTR];

    f32x4 acc[10];
    #pragma unroll
    for (int nt = 0; nt < 10; ++nt) acc[nt] = f32x4{0.f, 0.f, 0.f, 0.f};

    const unsigned short* Wbase = Wo + (size_t)slice * 160 * 1408;

    for (int kc = 0; kc < 4; ++kc) {
        __syncthreads();   // all waves done with previous chunk's Ash
        #pragma unroll
        for (int r = 0; r < 11; ++r) {
            int s = t + 256 * r;          // 2816 = 64 tok x 44 groups-of-8
            int tok = s / 44, g = s % 44;
            int f0 = kc * 352 + g * 8;
            uint4 val;
            if (f0 < 1280) {
                int hh = f0 / 160, pp = f0 % 160;
                val = *(const uint4*)(Hb + ((size_t)(b * H_ + hh) * NQ + n0 + tok) * DF + pp);
            } else if (f0 == 1280) {
                val.x = 0x3F80u; val.y = 0; val.z = 0; val.w = 0;  // bias feature = 1.0
            } else {
                val.x = 0; val.y = 0; val.z = 0; val.w = 0;
            }
            *(uint4*)&Ash[tok][g * 8] = val;
        }
        __syncthreads();

        bf16x8 af[11];
        #pragma unroll
        for (int ks = 0; ks < 11; ++ks)
            af[ks] = *(const bf16x8*)&Ash[w * 16 + l16][ks * 32 + lq * 8];

        for (int ks = 0; ks < 11; ++ks) {
            __syncthreads();
            #pragma unroll
            for (int r = 0; r < 3; ++r) {
                int s = t + 256 * r;
                if (s < 640) {
                    int row = s >> 2, c4 = s & 3;
                    *(uint4*)&Wsh[row][c4 * 8] =
                        *(const uint4*)(Wbase + (size_t)row * 1408 + kc * 352 + ks * 32 + c4 * 8);
                }
            }
            __syncthreads();
            #pragma unroll
            for (int nt = 0; nt < 10; ++nt) {
                bf16x8 wf = *(const bf16x8*)&Wsh[nt * 16 + l16][lq * 8];
                acc[nt] = __builtin_amdgcn_mfma_f32_16x16x32_bf16(af[ks], wf, acc[nt], 0, 0, 0);
            }
        }
    }

    const size_t sbase = (size_t)B_ * NQ * 256;
    #pragma unroll
    for (int nt = 0; nt < 10; ++nt) {
        int j = slice * 160 + nt * 16 + l16;
        #pragma unroll
        for (int r = 0; r < 4; ++r) {
            size_t tok = tok0 + w * 16 + 4 * lq + r;
            if (j < 256) out[tok * 256 + j] = acc[nt][r];
            else         out[sbase + tok * 64 + (j - 256)] = acc[nt][r];
        }
    }
}

// ---------------- flash attention, 2 heads/block (unchanged from round 4) --------
__global__ __launch_bounds__(256, 2) void attn_kernel(
    const unsigned short* __restrict__ Qb,
    const unsigned short* __restrict__ Kb0,
    const unsigned short* __restrict__ Vb0,
    const float* __restrict__ head_scale,
    unsigned short* __restrict__ Hb)   // [B][H][NQ][160] bf16
{
    const int qt = blockIdx.x, hp = blockIdx.y, b = blockIdx.z;
    const int tid  = threadIdx.x;
    const int w    = tid >> 6;
    const int lane = tid & 63;
    const int l16  = lane & 15;
    const int lq   = lane >> 4;
    const int qbase = qt * 64;

    __shared__ __align__(16) unsigned short Ksh[64][168];
    __shared__ __align__(16) unsigned short Vsh[160][72];
    __shared__ __align__(16) unsigned short Psh[2][4][16][72];

    bf16x8 onesf;
    #pragma unroll
    for (int j = 0; j < 8; ++j) onesf[j] = (short)0x3F80;

    bf16x8 qf[2][5];
    #pragma unroll
    for (int s = 0; s < 2; ++s) {
        const unsigned short* qrow =
            Qb + ((size_t)(b * H_ + hp * 2 + s) * NQ + qbase + w * 16 + l16) * DF;
        #pragma unroll
        for (int ks = 0; ks < 5; ++ks)
            qf[s][ks] = *reinterpret_cast<const bf16x8*>(qrow + ks * 32 + lq * 8);
    }

    f32x4 O[2][11];
    #pragma unroll
    for (int s = 0; s < 2; ++s)
        #pragma unroll
        for (int d = 0; d < 11; ++d) O[s][d] = f32x4{0.f, 0.f, 0.f, 0.f};

    const unsigned short* Kb = Kb0 + (size_t)b * NKV * DF;
    const unsigned short* Vb = Vb0 + (size_t)b * DF * NKV;

    for (int kt = 0; kt < NKV / 64; ++kt) {
        __syncthreads();
        #pragma unroll
        for (int c = 0; c < 5; ++c) {
            int idx = tid + c * 256;
            int r = idx / 20, col = idx % 20;
            *reinterpret_cast<uint4*>(&Ksh[r][col * 8]) =
                *reinterpret_cast<const uint4*>(Kb + (size_t)(kt * 64 + r) * DF + col * 8);
        }
        #pragma unroll
        for (int c = 0; c < 5; ++c) {
            int idx = tid + c * 256;
            int r = idx >> 3, col = idx & 7;
            *reinterpret_cast<uint4*>(&Vsh[r][col * 8]) =
                *reinterpret_cast<const uint4*>(Vb + (size_t)r * NKV + kt * 64 + col * 8);
        }
        __syncthreads();

        f32x4 sc[2][4];
        #pragma unroll
        for (int nt = 0; nt < 4; ++nt) {
            sc[0][nt] = f32x4{0.f, 0.f, 0.f, 0.f};
            sc[1][nt] = f32x4{0.f, 0.f, 0.f, 0.f};
            #pragma unroll
            for (int ks = 0; ks < 5; ++ks) {
                bf16x8 kf = *reinterpret_cast<const bf16x8*>(
                    &Ksh[nt * 16 + l16][ks * 32 + lq * 8]);
                sc[0][nt] = __builtin_amdgcn_mfma_f32_16x16x32_bf16(qf[0][ks], kf, sc[0][nt], 0, 0, 0);
                sc[1][nt] = __builtin_amdgcn_mfma_f32_16x16x32_bf16(qf[1][ks], kf, sc[1][nt], 0, 0, 0);
            }
        }

        #pragma unroll
        for (int s = 0; s < 2; ++s)
            #pragma unroll
            for (int nt = 0; nt < 4; ++nt)
                #pragma unroll
                for (int r = 0; r < 4; ++r)
                    Psh[s][w][lq * 4 + r][nt * 16 + l16] =
                        f2bf(__builtin_amdgcn_exp2f(sc[s][nt][r]));

        #pragma unroll
        for (int k2 = 0; k2 < 2; ++k2) {
            bf16x8 pf0 = *reinterpret_cast<const bf16x8*>(&Psh[0][w][l16][k2 * 32 + lq * 8]);
            bf16x8 pf1 = *reinterpret_cast<const bf16x8*>(&Psh[1][w][l16][k2 * 32 + lq * 8]);
            O[0][10] = __builtin_amdgcn_mfma_f32_16x16x32_bf16(pf0, onesf, O[0][10], 0, 0, 0);
            O[1][10] = __builtin_amdgcn_mfma_f32_16x16x32_bf16(pf1, onesf, O[1][10], 0, 0, 0);
            #pragma unroll
            for (int d = 0; d < 10; ++d) {
                bf16x8 vf = *reinterpret_cast<const bf16x8*>(
                    &Vsh[d * 16 + l16][k2 * 32 + lq * 8]);
                O[0][d] = __builtin_amdgcn_mfma_f32_16x16x32_bf16(pf0, vf, O[0][d], 0, 0, 0);
                O[1][d] = __builtin_amdgcn_mfma_f32_16x16x32_bf16(pf1, vf, O[1][d], 0, 0, 0);
            }
        }
    }

    #pragma unroll
    for (int s = 0; s < 2; ++s) {
        float hsc = head_scale[hp * 2 + s];
        #pragma unroll
        for (int r = 0; r < 4; ++r) {
            float inv = hsc / O[s][10][r];
            int qrow = qbase + w * 16 + lq * 4 + r;
            unsigned short* orow =
                Hb + ((size_t)(b * H_ + hp * 2 + s) * NQ + qrow) * DF;
            #pragma unroll
            for (int d = 0; d < 10; ++d)
                orow[d * 16 + l16] = f2bf(O[s][d][r] * inv);
        }
    }
}

extern "C" void kernel_launch(void* const* d_in, const int* in_sizes, int n_in,
                              void* d_out, int out_size, void* d_ws, size_t ws_size,
                              hipStream_t stream) {
    const float* mv_kv  = (const float*)d_in[0];
    const float* mv_q   = (const float*)d_in[1];
    const float* s_kv   = (const float*)d_in[2];
    const float* s_q    = (const float*)d_in[3];
    const float* wq_mv  = (const float*)d_in[4];
    const float* wq_s2mv= (const float*)d_in[5];
    const float* wq_mv2s= (const float*)d_in[6];
    const float* wq_s   = (const float*)d_in[7];
    const float* bq_mv  = (const float*)d_in[8];
    const float* bq_s   = (const float*)d_in[9];
    const float* wkv_mv = (const float*)d_in[10];
    const float* wkv_s2mv=(const float*)d_in[11];
    const float* wkv_mv2s=(const float*)d_in[12];
    const float* wkv_s  = (const float*)d_in[13];
    const float* bkv_mv = (const float*)d_in[14];
    const float* bkv_s  = (const float*)d_in[15];
    const float* wo_mv  = (const float*)d_in[16];
    const float* wo_s2mv= (const float*)d_in[17];
    const float* wo_mv2s= (const float*)d_in[18];
    const float* wo_s   = (const float*)d_in[19];
    const float* bo_mv  = (const float*)d_in[20];
    const float* bo_s   = (const float*)d_in[21];
    const float* head_scale = (const float*)d_in[22];

    char* ws = (char*)d_ws;
    unsigned short* Qbuf  = (unsigned short*)(ws);              // 20,971,520 B
    unsigned short* Kbuf  = (unsigned short*)(ws + 20971520);   //  2,621,440 B
    unsigned short* Vtbuf = (unsigned short*)(ws + 23592960);   //  2,621,440 B
    unsigned short* Hbuf  = (unsigned short*)(ws + 26214400);   // 20,971,520 B
    unsigned short* Wq    = (unsigned short*)(ws + 47185920);   //    901,120 B
    unsigned short* Wkv   = (unsigned short*)(ws + 48087040);   //    225,280 B
    unsigned short* Wo    = (unsigned short*)(ws + 48312320);   //    901,120 B

    expand_wq <<<1280, 256, 0, stream>>>(wq_mv, wq_s2mv, wq_mv2s, wq_s, bq_mv, bq_s, Wq);
    expand_wkv<<<320, 256, 0, stream>>>(wkv_mv, wkv_s2mv, wkv_mv2s, wkv_s, bkv_mv, bkv_s, Wkv);
    expand_wo <<<320, 256, 0, stream>>>(wo_mv, wo_s2mv, wo_mv2s, wo_s, bo_mv, bo_s, Wo);

    gemm_q <<<dim3(128, 8), 256, 0, stream>>>(mv_q, s_q, Wq, Qbuf);
    gemm_kv<<<dim3(128, 2), 256, 0, stream>>>(mv_kv, s_kv, Wkv, Kbuf, Vtbuf);

    dim3 g3(NQ / 64, H_ / 2, B_);
    attn_kernel<<<g3, 256, 0, stream>>>(Qbuf, Kbuf, Vtbuf, head_scale, Hbuf);

    gemm_o<<<dim3(128, 2), 256, 0, stream>>>(Hbuf, Wo, (float*)d_out);
}